// Round 2
// baseline (440.041 us; speedup 1.0000x reference)
//
#include <hip/hip_runtime.h>
#include <stdint.h>

#define DI __device__ __forceinline__

typedef __bf16 bf16x8 __attribute__((ext_vector_type(8)));
typedef float f32x4 __attribute__((ext_vector_type(4)));
typedef unsigned short u16;

// ---------- helpers ----------
DI u16 f2bf(float f) {
  union { float f; uint32_t u; } x; x.f = f;
  uint32_t r = (x.u + 0x7FFFu + ((x.u >> 16) & 1u)) >> 16;
  return (u16)r;
}
DI float bf2f(u16 b) {
  union { uint32_t u; float f; } x; x.u = ((uint32_t)b) << 16;
  return x.f;
}
DI bf16x8 load16(const u16* p) { return *(const bf16x8*)p; }

DI void async_copy16(void* lds, const void* g) {
  __builtin_amdgcn_global_load_lds(
      (const __attribute__((address_space(1))) uint32_t*)g,
      (__attribute__((address_space(3))) uint32_t*)lds, 16, 0, 0);
}

DI f32x4 mfma16(bf16x8 a, bf16x8 b, f32x4 c) {
  return __builtin_amdgcn_mfma_f32_16x16x32_bf16(a, b, c, 0, 0, 0);
}

DI float redmax16(float v) {  // max across 16-lane group (xor 1,2,4,8)
  v = fmaxf(v, __shfl_xor(v, 1));
  v = fmaxf(v, __shfl_xor(v, 2));
  v = fmaxf(v, __shfl_xor(v, 4));
  v = fmaxf(v, __shfl_xor(v, 8));
  return v;
}
DI float redsum16(float v) {
  v += __shfl_xor(v, 1);
  v += __shfl_xor(v, 2);
  v += __shfl_xor(v, 4);
  v += __shfl_xor(v, 8);
  return v;
}

// ---------- fp32 -> bf16 conversion (n % 4 == 0) ----------
__global__ __launch_bounds__(256)
void cvt_f32_bf16(const float* __restrict__ src, u16* __restrict__ dst, int n) {
  int i = (blockIdx.x * 256 + threadIdx.x) * 4;
  if (i < n) {
    float4 v = *(const float4*)(src + i);
    ushort4 o;
    o.x = f2bf(v.x); o.y = f2bf(v.y); o.z = f2bf(v.z); o.w = f2bf(v.w);
    *(ushort4*)(dst + i) = o;
  }
}

// ---------- GEMM: C[m,n] = sum_k A[m,k] * B[n,k]  (+bias[n]) ----------
// A: [M,K] bf16 row-major, B: [N,K] bf16 row-major.
// C: bf16 (F32OUT=false) or fp32 (F32OUT=true). bias: fp32.
// 128x128 tile, BK=32, 256 threads (4 waves, each 64x64 = 4x4 MFMA tiles).
template <bool BIAS, bool F32OUT>
__global__ __launch_bounds__(256)
void gemm_bt(const u16* __restrict__ A, const u16* __restrict__ Bm,
             const float* __restrict__ bias, void* __restrict__ Co,
             int M, int N, int K) {
  __shared__ u16 As[128 * 32];
  __shared__ u16 Bs[128 * 32];

  const int tid  = threadIdx.x;
  const int lane = tid & 63;
  const int wave = tid >> 6;
  const int m0 = blockIdx.y * 128;
  const int n0 = blockIdx.x * 128;
  const int wm = (wave & 1) * 64;
  const int wn = (wave >> 1) * 64;
  const int c = lane & 15;
  const int g = lane >> 4;

  f32x4 acc[4][4] = {};

  for (int k0 = 0; k0 < K; k0 += 32) {
#pragma unroll
    for (int i = 0; i < 2; ++i) {
      int j = i * 256 + tid;           // chunk id: row j>>2, col (j&3)*8
      int row = j >> 2;
      int col = (j & 3) * 8;
      async_copy16(&As[j * 8], &A[(size_t)(m0 + row) * K + k0 + col]);
      async_copy16(&Bs[j * 8], &Bm[(size_t)(n0 + row) * K + k0 + col]);
    }
    __syncthreads();

    bf16x8 af[4], bfr[4];
#pragma unroll
    for (int t = 0; t < 4; ++t) {
      af[t]  = *(const bf16x8*)&As[(wm + t * 16 + c) * 32 + g * 8];
      bfr[t] = *(const bf16x8*)&Bs[(wn + t * 16 + c) * 32 + g * 8];
    }
#pragma unroll
    for (int mt = 0; mt < 4; ++mt)
#pragma unroll
      for (int nt = 0; nt < 4; ++nt)
        acc[mt][nt] = mfma16(af[mt], bfr[nt], acc[mt][nt]);
    __syncthreads();
  }

  // epilogue: C/D layout col = lane&15, row = (lane>>4)*4 + reg
#pragma unroll
  for (int nt = 0; nt < 4; ++nt) {
    int col = n0 + wn + nt * 16 + c;
    float bv = BIAS ? bias[col] : 0.f;
#pragma unroll
    for (int mt = 0; mt < 4; ++mt) {
#pragma unroll
      for (int r = 0; r < 4; ++r) {
        int row = m0 + wm + mt * 16 + g * 4 + r;
        if (F32OUT)
          ((float*)Co)[(size_t)row * N + col] = acc[mt][nt][r] + bv;
        else
          ((u16*)Co)[(size_t)row * N + col] = f2bf(acc[mt][nt][r] + bv);
      }
    }
  }
}

// ---------- Flash attention ----------
// qkv: [B*N, 2304] bf16 (q|k|v each 768 = 12 heads * 64)
// out: [B*N, 768] bf16  ([B,N,H,HD] flattened)
// grid.x = B*H*(N/64); block = 256 (4 waves); each wave: 16 q-rows, full k loop.
__global__ __launch_bounds__(256)
void attn_flash(const u16* __restrict__ qkv, u16* __restrict__ out) {
  const int tid  = threadIdx.x;
  const int lane = tid & 63;
  const int wave = tid >> 6;
  const int idx = blockIdx.x;
  const int qchunk = idx & 31;        // N/64 = 32
  const int h = (idx >> 5) % 12;
  const int b = idx / (32 * 12);
  const int q0 = qchunk * 64 + wave * 16;
  const int c = lane & 15;
  const int g = lane >> 4;

  const size_t bh = (size_t)b * 2048 * 2304 + (size_t)h * 64;
  const u16* Qp = qkv + bh;          // row stride 2304
  const u16* Kp = Qp + 768;
  const u16* Vp = Qp + 1536;

  // per-wave P scratch: 16 rows x 32 cols, row stride 56 elems (112B, 16B-aligned)
  __shared__ u16 Plds[4][16 * 56];
  u16* pw = &Plds[wave][0];

  // Q A-fragments (row l&15, k = g*8+j), two d-halves
  const bf16x8 qf0 = load16(&Qp[(size_t)(q0 + c) * 2304 + g * 8]);
  const bf16x8 qf1 = load16(&Qp[(size_t)(q0 + c) * 2304 + 32 + g * 8]);

  const float cs = 0.125f * 1.44269504088896340736f;  // scale * log2(e)

  float m[4]    = {-INFINITY, -INFINITY, -INFINITY, -INFINITY};
  float lsum[4] = {0.f, 0.f, 0.f, 0.f};
  f32x4 o[4] = {};

  for (int k0 = 0; k0 < 2048; k0 += 32) {
    // K^T B-fragments: lane holds K[k0 + t*16 + c][dh*32 + g*8 + j]
    const bf16x8 kf00 = load16(&Kp[(size_t)(k0 + c) * 2304 + g * 8]);
    const bf16x8 kf01 = load16(&Kp[(size_t)(k0 + c) * 2304 + 32 + g * 8]);
    const bf16x8 kf10 = load16(&Kp[(size_t)(k0 + 16 + c) * 2304 + g * 8]);
    const bf16x8 kf11 = load16(&Kp[(size_t)(k0 + 16 + c) * 2304 + 32 + g * 8]);

    f32x4 s0 = {}, s1 = {};
    s0 = mfma16(qf0, kf00, s0);
    s0 = mfma16(qf1, kf01, s0);
    s1 = mfma16(qf0, kf10, s1);
    s1 = mfma16(qf1, kf11, s1);

    float al[4], p0[4], p1[4];
#pragma unroll
    for (int r = 0; r < 4; ++r) {
      float t0 = s0[r] * cs;
      float t1 = s1[r] * cs;
      float v = redmax16(fmaxf(t0, t1));
      float mn = fmaxf(m[r], v);
      al[r] = exp2f(m[r] - mn);
      m[r] = mn;
      p0[r] = exp2f(t0 - mn);
      p1[r] = exp2f(t1 - mn);
      float rs = redsum16(p0[r] + p1[r]);
      lsum[r] = lsum[r] * al[r] + rs;
    }
    // rescale O accumulators
#pragma unroll
    for (int dt = 0; dt < 4; ++dt)
#pragma unroll
      for (int r = 0; r < 4; ++r) o[dt][r] *= al[r];

    // P: C-layout -> LDS (bf16) -> A-layout
#pragma unroll
    for (int r = 0; r < 4; ++r) {
      pw[(g * 4 + r) * 56 + c]      = f2bf(p0[r]);
      pw[(g * 4 + r) * 56 + 16 + c] = f2bf(p1[r]);
    }
    __asm__ volatile("s_waitcnt lgkmcnt(0)" ::: "memory");
    const bf16x8 pf = *(const bf16x8*)&pw[c * 56 + g * 8];

    // PV: B-fragment = V[k0 + g*8 + j][dt*16 + c], scalar loads
#pragma unroll
    for (int dt = 0; dt < 4; ++dt) {
      union { u16 s[8]; bf16x8 v; } vf;
      const u16* vbase = Vp + (size_t)(k0 + g * 8) * 2304 + dt * 16 + c;
#pragma unroll
      for (int j = 0; j < 8; ++j) vf.s[j] = vbase[(size_t)j * 2304];
      o[dt] = mfma16(pf, vf.v, o[dt]);
    }
  }

  float inv[4];
#pragma unroll
  for (int r = 0; r < 4; ++r) inv[r] = 1.f / lsum[r];
#pragma unroll
  for (int dt = 0; dt < 4; ++dt)
#pragma unroll
    for (int r = 0; r < 4; ++r) {
      int n = q0 + g * 4 + r;
      out[(size_t)(b * 2048 + n) * 768 + h * 64 + dt * 16 + c] =
          f2bf(o[dt][r] * inv[r]);
    }
}

// ---------- launcher ----------
extern "C" void kernel_launch(void* const* d_in, const int* in_sizes, int n_in,
                              void* d_out, int out_size, void* d_ws, size_t ws_size,
                              hipStream_t stream) {
  const float* x      = (const float*)d_in[0];  // [4,2048,768] fp32
  const float* w_qkv  = (const float*)d_in[1];  // [2304,768]
  const float* w_proj = (const float*)d_in[2];  // [768,768]
  const float* b_proj = (const float*)d_in[3];  // [768]
  float* out = (float*)d_out;                   // [4,2048,768] fp32

  const int M = 8192;     // B*N
  const int C = 768;
  const int NQKV = 2304;

  // workspace layout (bf16 elements)
  u16* xb     = (u16*)d_ws;                        // 8192*768
  u16* wqkvb  = xb + (size_t)M * C;                // 2304*768
  u16* wprojb = wqkvb + (size_t)NQKV * C;          // 768*768
  u16* qkv    = wprojb + (size_t)C * C;            // 8192*2304
  u16* attn   = qkv + (size_t)M * NQKV;            // 8192*768

  dim3 blk(256);
  // 0) convert fp32 inputs to bf16
  cvt_f32_bf16<<<dim3(M * C / 1024), blk, 0, stream>>>(x, xb, M * C);
  cvt_f32_bf16<<<dim3(NQKV * C / 1024), blk, 0, stream>>>(w_qkv, wqkvb, NQKV * C);
  cvt_f32_bf16<<<dim3(C * C / 1024), blk, 0, stream>>>(w_proj, wprojb, C * C);

  // 1) qkv = x @ w_qkv^T   (bf16 out)
  gemm_bt<false, false><<<dim3(NQKV / 128, M / 128), blk, 0, stream>>>(
      xb, wqkvb, nullptr, qkv, M, NQKV, C);
  // 2) flash attention (bf16 in/out)
  attn_flash<<<dim3(4 * 12 * 32), blk, 0, stream>>>(qkv, attn);
  // 3) out = attn @ w_proj^T + b   (fp32 out)
  gemm_bt<true, true><<<dim3(C / 128, M / 128), blk, 0, stream>>>(
      attn, wprojb, b_proj, out, M, C, C);
}